// Round 17
// baseline (123.059 us; speedup 1.0000x reference)
//
#include <hip/hip_runtime.h>

typedef unsigned short u16;
typedef float f32x4 __attribute__((ext_vector_type(4)));
typedef __bf16 bf16x8 __attribute__((ext_vector_type(8)));
typedef __bf16 bf16x4 __attribute__((ext_vector_type(4)));

#define DEV static __device__ __forceinline__

constexpr int kB = 2;
constexpr int kL = 2048;
constexpr int kD = 1024;
constexpr int kH = 16;
constexpr int kP = 64;
constexpr int kM = kB * kL;  // 4096 tokens
constexpr float kQScale = 0.125f * 1.44269504088896f;  // 1/sqrt(P) * log2(e)

DEV u16 f2bf(float x) {
  union { float f; unsigned u; } v;
  v.f = x;
  unsigned r = v.u + 0x7fffu + ((v.u >> 16) & 1u);  // round-to-nearest-even
  return (u16)(r >> 16);
}

DEV void gload16(const void* g, void* l) {
  __builtin_amdgcn_global_load_lds(
      (const __attribute__((address_space(1))) unsigned int*)g,
      (__attribute__((address_space(3))) unsigned int*)l, 16, 0, 0);
}

// ---------------------------------------------------------------- convert
// single launch: i < 2^20 -> x (1M float4); else weights (4 x 2^18 float4)
__global__ void cvt_all(const float* __restrict__ x,
                        const float* __restrict__ w0, const float* __restrict__ w1,
                        const float* __restrict__ w2, const float* __restrict__ w3,
                        u16* __restrict__ xb,
                        u16* __restrict__ o0, u16* __restrict__ o1,
                        u16* __restrict__ o2, u16* __restrict__ o3) {
  int i = blockIdx.x * blockDim.x + threadIdx.x;
  const float* src;
  u16* dst;
  int j;
  if (i < (1 << 20)) {
    src = x; dst = xb; j = i;
  } else {
    int s = (i >> 18) & 3;
    j = i & ((1 << 18) - 1);
    src = s == 0 ? w0 : (s == 1 ? w1 : (s == 2 ? w2 : w3));
    dst = s == 0 ? o0 : (s == 1 ? o1 : (s == 2 ? o2 : o3));
  }
  float4 v = reinterpret_cast<const float4*>(src)[j];
  uint2 o;
  o.x = (unsigned)f2bf(v.x) | ((unsigned)f2bf(v.y) << 16);
  o.y = (unsigned)f2bf(v.z) | ((unsigned)f2bf(v.w) << 16);
  reinterpret_cast<uint2*>(dst)[j] = o;
}

// ---------------------------------------------------------------- GEMM core (R10-proven, 4 waves)
// C[m,n] = sum_k A[m,k]*W[n,k], K=kD. 128x128 tile, BK=32, 2-barrier loop,
// 4-slot LDS swizzle both-sides.
template <bool SWAP>
DEV void gemm_tile(const u16* __restrict__ A, const u16* __restrict__ W,
                   int m0, int n0, u16* As, u16* Bs, f32x4 acc[4][4]) {
  const int tid = threadIdx.x;
  const int w = tid >> 6, lane = tid & 63;
  const int wr = w >> 1, wc = w & 1;
  const int g = lane >> 4, c = lane & 15;
  const int srow = lane >> 2;                            // row 0..15 in stripe
  const int skoff = ((lane & 3) ^ (srow & 3)) * 8;       // swizzled source slot
  const int rsl0 = (g ^ (c & 3)) * 8;                    // swizzled read slot

  for (int k0 = 0; k0 < kD; k0 += 32) {
    __syncthreads();
#pragma unroll
    for (int j = 0; j < 2; ++j) {
      const u16* ga = A + (size_t)(m0 + w * 32 + j * 16 + srow) * kD + k0 + skoff;
      gload16(ga, As + (w * 32 + j * 16) * 32);
      const u16* gb = W + (size_t)(n0 + w * 32 + j * 16 + srow) * kD + k0 + skoff;
      gload16(gb, Bs + (w * 32 + j * 16) * 32);
    }
    __syncthreads();

    bf16x8 af[4], bfr[4];
#pragma unroll
    for (int f = 0; f < 4; ++f) {
      af[f]  = *reinterpret_cast<const bf16x8*>(As + (wr * 64 + f * 16 + c) * 32 + rsl0);
      bfr[f] = *reinterpret_cast<const bf16x8*>(Bs + (wc * 64 + f * 16 + c) * 32 + rsl0);
    }
#pragma unroll
    for (int fi = 0; fi < 4; ++fi)
#pragma unroll
      for (int fj = 0; fj < 4; ++fj) {
        if constexpr (SWAP)
          acc[fj][fi] = __builtin_amdgcn_mfma_f32_16x16x32_bf16(bfr[fj], af[fi], acc[fj][fi], 0, 0, 0);
        else
          acc[fi][fj] = __builtin_amdgcn_mfma_f32_16x16x32_bf16(af[fi], bfr[fj], acc[fi][fj], 0, 0, 0);
      }
  }
}

// ---------------------------------------------------------------- QKV GEMM (R10-proven)
// 1D grid 768 = 8 XCDs x 96, XCD-chunked: logical = (hw&7)*96 + hw>>3.
__global__ __launch_bounds__(256) void qkv_kernel(
    const u16* __restrict__ xb,
    const u16* __restrict__ wq, const u16* __restrict__ wk, const u16* __restrict__ wv,
    const float* __restrict__ bq, const float* __restrict__ bk, const float* __restrict__ bv,
    u16* __restrict__ qb, u16* __restrict__ kb, u16* __restrict__ vtb) {
  __shared__ u16 As[128 * 32], Bs[128 * 32];
  const int hw = blockIdx.x;
  const int logical = (hw & 7) * 96 + (hw >> 3);
  const int mb = logical & 31, nb = logical >> 5;
  const int sel = nb >> 3;
  const int m0 = mb * 128, n0 = (nb & 7) * 128;
  const u16* W = sel == 0 ? wq : (sel == 1 ? wk : wv);
  const float* bias = sel == 0 ? bq : (sel == 1 ? bk : bv);

  const int lane = threadIdx.x & 63, w = threadIdx.x >> 6;
  const int wr = w >> 1, wc = w & 1, g = lane >> 4, c = lane & 15;
  const int bb = m0 >> 11;
  const int lbase = (m0 & 2047) + wr * 64;

  f32x4 acc[4][4];
#pragma unroll
  for (int i = 0; i < 4; ++i)
#pragma unroll
    for (int j = 0; j < 4; ++j) acc[i][j] = f32x4{0.f, 0.f, 0.f, 0.f};

  if (sel < 2) {  // Q or K: swapped -> reg-dim = n = (h,p); packed p-stores
    gemm_tile<true>(xb, W, m0, n0, As, Bs, acc);
    u16* dst = sel == 0 ? qb : kb;
    const float scale = (sel == 0) ? kQScale : 1.0f;
#pragma unroll
    for (int fj = 0; fj < 4; ++fj) {
      const int n4 = n0 + wc * 64 + fj * 16 + g * 4;
      const float4 b4 = *reinterpret_cast<const float4*>(&bias[n4]);
      const int hh = n4 >> 6, p0 = n4 & 63;
      u16* base = dst + ((size_t)(bb * kH + hh)) * kL * kP + p0;
#pragma unroll
      for (int fi = 0; fi < 4; ++fi) {
        const int l = lbase + fi * 16 + c;
        bf16x4 o;
        o[0] = (__bf16)((acc[fj][fi][0] + b4.x) * scale);
        o[1] = (__bf16)((acc[fj][fi][1] + b4.y) * scale);
        o[2] = (__bf16)((acc[fj][fi][2] + b4.z) * scale);
        o[3] = (__bf16)((acc[fj][fi][3] + b4.w) * scale);
        *reinterpret_cast<bf16x4*>(base + (size_t)l * kP) = o;
      }
    }
  } else {  // V: unswapped -> reg-dim = m = l; packed l-stores into V^T
    gemm_tile<false>(xb, W, m0, n0, As, Bs, acc);
#pragma unroll
    for (int fj = 0; fj < 4; ++fj) {
      const int n = n0 + wc * 64 + fj * 16 + c;
      const float bv_ = bias[n];
      const int hh = n >> 6, p = n & 63;
      u16* base = vtb + (((size_t)(bb * kH + hh)) * kP + p) * kL;
#pragma unroll
      for (int fi = 0; fi < 4; ++fi) {
        const int l4 = lbase + fi * 16 + g * 4;
        bf16x4 o;
#pragma unroll
        for (int r = 0; r < 4; ++r) o[r] = (__bf16)(acc[fi][fj][r] + bv_);
        *reinterpret_cast<bf16x4*>(base + l4) = o;
      }
    }
  }
}

// ---------------------------------------------------------------- output GEMM (R10-proven)
// 8 waves (512 thr), 128x128 tile, wave tile 64x32 (wr=w>>2, wc=w&3).
// Grid 256 = 1 block/CU. XCD-chunked: logical = (hw&7)*32 + hw>>3.
__global__ __launch_bounds__(512) void out_kernel(
    const u16* __restrict__ ob, const u16* __restrict__ wo,
    const float* __restrict__ bo, float* __restrict__ out) {
  __shared__ u16 As[128 * 32], Bs[128 * 32];
  const int hw = blockIdx.x;
  const int logical = (hw & 7) * 32 + (hw >> 3);
  const int m0 = (logical & 31) * 128, n0 = (logical >> 5) * 128;

  const int tid = threadIdx.x;
  const int w = tid >> 6, lane = tid & 63;
  const int wr = w >> 2, wc = w & 3;
  const int g = lane >> 4, c = lane & 15;
  const int srow = lane >> 2;
  const int skoff = ((lane & 3) ^ (srow & 3)) * 8;
  const int rsl0 = (g ^ (c & 3)) * 8;

  f32x4 acc[2][4];
#pragma unroll
  for (int i = 0; i < 2; ++i)
#pragma unroll
    for (int j = 0; j < 4; ++j) acc[i][j] = f32x4{0.f, 0.f, 0.f, 0.f};

  for (int k0 = 0; k0 < kD; k0 += 32) {
    __syncthreads();
    {  // each wave stages 16 rows of A and of W
      const u16* ga = ob + (size_t)(m0 + w * 16 + srow) * kD + k0 + skoff;
      gload16(ga, As + (w * 16) * 32);
      const u16* gb = wo + (size_t)(n0 + w * 16 + srow) * kD + k0 + skoff;
      gload16(gb, Bs + (w * 16) * 32);
    }
    __syncthreads();

    bf16x8 af[4], bfr[2];
#pragma unroll
    for (int f = 0; f < 4; ++f)
      af[f] = *reinterpret_cast<const bf16x8*>(As + (wr * 64 + f * 16 + c) * 32 + rsl0);
#pragma unroll
    for (int f = 0; f < 2; ++f)
      bfr[f] = *reinterpret_cast<const bf16x8*>(Bs + (wc * 32 + f * 16 + c) * 32 + rsl0);
#pragma unroll
    for (int fj = 0; fj < 2; ++fj)
#pragma unroll
      for (int fi = 0; fi < 4; ++fi)
        acc[fj][fi] = __builtin_amdgcn_mfma_f32_16x16x32_bf16(bfr[fj], af[fi], acc[fj][fi], 0, 0, 0);
  }

  // epilogue: reg-dim = n -> float4 stores
#pragma unroll
  for (int fj = 0; fj < 2; ++fj) {
    const int n4 = n0 + wc * 32 + fj * 16 + g * 4;
    const float4 b4 = *reinterpret_cast<const float4*>(&bo[n4]);
#pragma unroll
    for (int fi = 0; fi < 4; ++fi) {
      const int m = m0 + wr * 64 + fi * 16 + c;
      float4 o;
      o.x = acc[fj][fi][0] + b4.x;
      o.y = acc[fj][fi][1] + b4.y;
      o.z = acc[fj][fi][2] + b4.z;
      o.w = acc[fj][fi][3] + b4.w;
      *reinterpret_cast<float4*>(&out[(size_t)m * kD + n4]) = o;
    }
  }
}

// ---------------------------------------------------------------- flash attention
// R16 core + KVBLK=128: per barrier, stage 4 sub-tiles {K0,K1,V0,V1} (each
// identical in layout/swizzle to the proven 64-key tiles), then run the
// proven 64-key compute body TWICE (P^T bounce is per-wave -> no cross-wave
// hazard between halves), then ONE __syncthreads. Halves the drain events;
// staged loads get ~2x compute to land under. LDS 80KB -> 2 blocks/CU
// (same as the grid-capped residency today, so no occupancy loss).
// 1D grid 512 = 8 XCDs x 64, XCD-chunked (K/V L2-resident per XCD).
__global__ __launch_bounds__(512, 2) void attn_kernel(
    const u16* __restrict__ qb, const u16* __restrict__ kb,
    const u16* __restrict__ vtb, u16* __restrict__ ob) {
  // [buf][K0,K1,V0,V1][64 rows][128B, swizzled: 16B slot ^= row&7]
  __shared__ __align__(16) char kvs[2][4][8192];
  __shared__ __align__(16) char pts[8][2048];  // per-wave P^T [16][128B swizzled]
  const int tid = threadIdx.x, w = tid >> 6, lane = tid & 63;
  const int g = lane >> 4, c = lane & 15;
  const int hw = blockIdx.x;                      // 512 = 8 XCDs x 64
  const int logical = (hw & 7) * 64 + (hw >> 3);  // bijective
  const int qblk = logical & 15;
  const int hb = logical >> 4;                    // 0..31
  const int h = hb & 15, b = hb >> 4;
  const size_t hoff = ((size_t)(b * kH + h)) * kL * kP;
  const char* Qg = (const char*)(qb + hoff);
  const char* Kg = (const char*)(kb + hoff);
  const char* Vg = (const char*)(vtb + hoff);
  const int q0 = qblk * 128 + w * 16;

  // ---- staging: wave w stages rows w*8..w*8+7 of each 64-row sub-tile
  const int lrow = lane >> 3;
  const int spb = ((lane & 7) ^ lrow) << 4;  // pre-swizzled source byte col
  const char* kp = Kg + (size_t)(w * 8 + lrow) * 128 + spb;
  const char* vp = Vg + (size_t)(w * 8 + lrow) * (kL * 2) + spb;

  auto stage = [&](int buf) {
    gload16(kp,            &kvs[buf][0][w * 1024]);  // keys l0..l0+63
    gload16(kp + 64 * 128, &kvs[buf][1][w * 1024]);  // keys l0+64..l0+127
    gload16(vp,            &kvs[buf][2][w * 1024]);  // V^T, keys l0..
    gload16(vp + 128,      &kvs[buf][3][w * 1024]);  // V^T, keys l0+64..
    kp += 128 * 128;  // next 128 key rows
    vp += 256;        // next 128 keys (2B each)
  };

  // ---- hoisted per-lane LDS byte offsets
  const int csw = (c & 7) << 4;
  const int kvb0 = c * 128 + ((g * 16) ^ csw);
  const int kvb1 = c * 128 + ((64 + g * 16) ^ csw);
  char* myPt = &pts[w][0];

  // Q fragments (16 rows x 64), hoisted
  bf16x8 qf[2];
#pragma unroll
  for (int kc = 0; kc < 2; ++kc)
    qf[kc] = *reinterpret_cast<const bf16x8*>(Qg + (size_t)(q0 + c) * 128 + kc * 64 + g * 16);

  f32x4 oacc[4];
#pragma unroll
  for (int pt = 0; pt < 4; ++pt) oacc[pt] = f32x4{0.f, 0.f, 0.f, 0.f};
  float Srun = 0.f;  // per-lane partial; reduced once at the end

  // proven 64-key compute body (unchanged from R16)
  auto half_compute = [&](const char* Ks, const char* Vs) {
    // QK^T: s[lt] = S[key = lt*16+g*4+r][query = c]  (exp2 domain)
    f32x4 s[4];
    __builtin_amdgcn_s_setprio(1);
#pragma unroll
    for (int lt = 0; lt < 4; ++lt) {
      bf16x8 k0 = *reinterpret_cast<const bf16x8*>(Ks + lt * 2048 + kvb0);
      bf16x8 k1 = *reinterpret_cast<const bf16x8*>(Ks + lt * 2048 + kvb1);
      f32x4 z = f32x4{0.f, 0.f, 0.f, 0.f};
      z = __builtin_amdgcn_mfma_f32_16x16x32_bf16(k0, qf[0], z, 0, 0, 0);
      z = __builtin_amdgcn_mfma_f32_16x16x32_bf16(k1, qf[1], z, 0, 0, 0);
      s[lt] = z;
    }
    __builtin_amdgcn_s_setprio(0);

    // P = exp2(s); pack bf16x4, swizzled 8B stores (XOR wraps FULL col offset)
    float tsum = 0.f;
#pragma unroll
    for (int lt = 0; lt < 4; ++lt) {
      bf16x4 pv;
#pragma unroll
      for (int r = 0; r < 4; ++r) {
        float p = __builtin_amdgcn_exp2f(s[lt][r]);
        tsum += p;
        pv[r] = (__bf16)p;
      }
      *reinterpret_cast<bf16x4*>(myPt + c * 128 + ((lt * 32 + g * 8) ^ csw)) = pv;
    }
    Srun += tsum;

    // PV: A = P^T rows (query), B = Vt rows (p)
    bf16x8 pf0 = *reinterpret_cast<const bf16x8*>(myPt + kvb0);
    bf16x8 pf1 = *reinterpret_cast<const bf16x8*>(myPt + kvb1);
    __builtin_amdgcn_s_setprio(1);
#pragma unroll
    for (int pt = 0; pt < 4; ++pt) {
      bf16x8 v0 = *reinterpret_cast<const bf16x8*>(Vs + pt * 2048 + kvb0);
      bf16x8 v1 = *reinterpret_cast<const bf16x8*>(Vs + pt * 2048 + kvb1);
      oacc[pt] = __builtin_amdgcn_mfma_f32_16x16x32_bf16(pf0, v0, oacc[pt], 0, 0, 0);
      oacc[pt] = __builtin_amdgcn_mfma_f32_16x16x32_bf16(pf1, v1, oacc[pt], 0, 0, 0);
    }
    __builtin_amdgcn_s_setprio(0);
  };

  stage(0);
  __syncthreads();

  constexpr int NT = kL / 128;  // 16 iterations of 128 keys
  auto body = [&](int cur, int t) {
    if (t + 1 < NT) stage(cur ^ 1);
    half_compute(&kvs[cur][0][0], &kvs[cur][2][0]);  // keys l0..l0+63
    half_compute(&kvs[cur][1][0], &kvs[cur][3][0]);  // keys l0+64..l0+127
    __syncthreads();  // drains prefetch + all waves done with buf[cur]
  };

  for (int t = 0; t < NT; t += 2) {
    body(0, t);
    body(1, t + 1);
  }

  // reduce Srun across the 4 lane-groups (same query c)
  Srun += __shfl_xor(Srun, 16, 64);
  Srun += __shfl_xor(Srun, 32, 64);

  // normalize, store to o_buf [B, L, D]
  float rs = 1.f / Srun;
  float fr[4];
#pragma unroll
  for (int r = 0; r < 4; ++r) fr[r] = __shfl(rs, g * 4 + r, 64);
#pragma unroll
  for (int pt = 0; pt < 4; ++pt)
#pragma unroll
    for (int r = 0; r < 4; ++r) {
      int q = q0 + g * 4 + r;
      ob[((size_t)(b * kL + q)) * kD + h * kP + pt * 16 + c] = f2bf(oacc[pt][r] * fr[r]);
    }
}

// ---------------------------------------------------------------- launch
extern "C" void kernel_launch(void* const* d_in, const int* in_sizes, int n_in,
                              void* d_out, int out_size, void* d_ws, size_t ws_size,
                              hipStream_t stream) {
  (void)in_sizes; (void)n_in; (void)out_size; (void)ws_size;
  const float* x  = (const float*)d_in[0];
  const float* Wq = (const float*)d_in[1];
  const float* bq = (const float*)d_in[2];
  const float* Wk = (const float*)d_in[3];
  const float* bk = (const float*)d_in[4];
  const float* Wv = (const float*)d_in[5];
  const float* bv = (const float*)d_in[6];
  const float* Wo = (const float*)d_in[7];
  const float* bo = (const float*)d_in[8];
  float* out = (float*)d_out;

  char* ws = (char*)d_ws;
  u16* xb  = (u16*)(ws);                     // 8 MiB; reused as o_buf after QKV
  u16* wqb = (u16*)(ws + (8u << 20));
  u16* wkb = (u16*)(ws + (10u << 20));
  u16* wvb = (u16*)(ws + (12u << 20));
  u16* wob = (u16*)(ws + (14u << 20));
  u16* qb  = (u16*)(ws + (16u << 20));       // [B,H,L,P] (pre-scaled, exp2 domain)
  u16* kb  = (u16*)(ws + (24u << 20));       // [B,H,L,P]
  u16* vtb = (u16*)(ws + (32u << 20));       // [B,H,P,L]

  cvt_all<<<8192, 256, 0, stream>>>(x, Wq, Wk, Wv, Wo, xb, wqb, wkb, wvb, wob);

  qkv_kernel<<<768, 256, 0, stream>>>(
      xb, wqb, wkb, wvb, bq, bk, bv, qb, kb, vtb);

  attn_kernel<<<512, 512, 0, stream>>>(qb, kb, vtb, xb);

  out_kernel<<<256, 512, 0, stream>>>(xb, wob, bo, out);
}

// Round 18
// 115.147 us; speedup vs baseline: 1.0687x; 1.0687x over previous
//
#include <hip/hip_runtime.h>

typedef unsigned short u16;
typedef float f32x4 __attribute__((ext_vector_type(4)));
typedef __bf16 bf16x8 __attribute__((ext_vector_type(8)));
typedef __bf16 bf16x4 __attribute__((ext_vector_type(4)));

#define DEV static __device__ __forceinline__

constexpr int kB = 2;
constexpr int kL = 2048;
constexpr int kD = 1024;
constexpr int kH = 16;
constexpr int kP = 64;
constexpr int kM = kB * kL;  // 4096 tokens
constexpr float kQScale = 0.125f * 1.44269504088896f;  // 1/sqrt(P) * log2(e)

DEV u16 f2bf(float x) {
  union { float f; unsigned u; } v;
  v.f = x;
  unsigned r = v.u + 0x7fffu + ((v.u >> 16) & 1u);  // round-to-nearest-even
  return (u16)(r >> 16);
}

DEV void gload16(const void* g, void* l) {
  __builtin_amdgcn_global_load_lds(
      (const __attribute__((address_space(1))) unsigned int*)g,
      (__attribute__((address_space(3))) unsigned int*)l, 16, 0, 0);
}

// ---------------------------------------------------------------- convert
// single launch: i < 2^20 -> x (1M float4); else weights (4 x 2^18 float4)
__global__ void cvt_all(const float* __restrict__ x,
                        const float* __restrict__ w0, const float* __restrict__ w1,
                        const float* __restrict__ w2, const float* __restrict__ w3,
                        u16* __restrict__ xb,
                        u16* __restrict__ o0, u16* __restrict__ o1,
                        u16* __restrict__ o2, u16* __restrict__ o3) {
  int i = blockIdx.x * blockDim.x + threadIdx.x;
  const float* src;
  u16* dst;
  int j;
  if (i < (1 << 20)) {
    src = x; dst = xb; j = i;
  } else {
    int s = (i >> 18) & 3;
    j = i & ((1 << 18) - 1);
    src = s == 0 ? w0 : (s == 1 ? w1 : (s == 2 ? w2 : w3));
    dst = s == 0 ? o0 : (s == 1 ? o1 : (s == 2 ? o2 : o3));
  }
  float4 v = reinterpret_cast<const float4*>(src)[j];
  uint2 o;
  o.x = (unsigned)f2bf(v.x) | ((unsigned)f2bf(v.y) << 16);
  o.y = (unsigned)f2bf(v.z) | ((unsigned)f2bf(v.w) << 16);
  reinterpret_cast<uint2*>(dst)[j] = o;
}

// ---------------------------------------------------------------- GEMM core (R10-proven, 4 waves)
// C[m,n] = sum_k A[m,k]*W[n,k], K=kD. 128x128 tile, BK=32, 2-barrier loop,
// 4-slot LDS swizzle both-sides.
template <bool SWAP>
DEV void gemm_tile(const u16* __restrict__ A, const u16* __restrict__ W,
                   int m0, int n0, u16* As, u16* Bs, f32x4 acc[4][4]) {
  const int tid = threadIdx.x;
  const int w = tid >> 6, lane = tid & 63;
  const int wr = w >> 1, wc = w & 1;
  const int g = lane >> 4, c = lane & 15;
  const int srow = lane >> 2;                            // row 0..15 in stripe
  const int skoff = ((lane & 3) ^ (srow & 3)) * 8;       // swizzled source slot
  const int rsl0 = (g ^ (c & 3)) * 8;                    // swizzled read slot

  for (int k0 = 0; k0 < kD; k0 += 32) {
    __syncthreads();
#pragma unroll
    for (int j = 0; j < 2; ++j) {
      const u16* ga = A + (size_t)(m0 + w * 32 + j * 16 + srow) * kD + k0 + skoff;
      gload16(ga, As + (w * 32 + j * 16) * 32);
      const u16* gb = W + (size_t)(n0 + w * 32 + j * 16 + srow) * kD + k0 + skoff;
      gload16(gb, Bs + (w * 32 + j * 16) * 32);
    }
    __syncthreads();

    bf16x8 af[4], bfr[4];
#pragma unroll
    for (int f = 0; f < 4; ++f) {
      af[f]  = *reinterpret_cast<const bf16x8*>(As + (wr * 64 + f * 16 + c) * 32 + rsl0);
      bfr[f] = *reinterpret_cast<const bf16x8*>(Bs + (wc * 64 + f * 16 + c) * 32 + rsl0);
    }
#pragma unroll
    for (int fi = 0; fi < 4; ++fi)
#pragma unroll
      for (int fj = 0; fj < 4; ++fj) {
        if constexpr (SWAP)
          acc[fj][fi] = __builtin_amdgcn_mfma_f32_16x16x32_bf16(bfr[fj], af[fi], acc[fj][fi], 0, 0, 0);
        else
          acc[fi][fj] = __builtin_amdgcn_mfma_f32_16x16x32_bf16(af[fi], bfr[fj], acc[fi][fj], 0, 0, 0);
      }
  }
}

// ---------------------------------------------------------------- QKV GEMM (R10-proven)
// 1D grid 768 = 8 XCDs x 96, XCD-chunked: logical = (hw&7)*96 + hw>>3.
__global__ __launch_bounds__(256) void qkv_kernel(
    const u16* __restrict__ xb,
    const u16* __restrict__ wq, const u16* __restrict__ wk, const u16* __restrict__ wv,
    const float* __restrict__ bq, const float* __restrict__ bk, const float* __restrict__ bv,
    u16* __restrict__ qb, u16* __restrict__ kb, u16* __restrict__ vtb) {
  __shared__ u16 As[128 * 32], Bs[128 * 32];
  const int hw = blockIdx.x;
  const int logical = (hw & 7) * 96 + (hw >> 3);
  const int mb = logical & 31, nb = logical >> 5;
  const int sel = nb >> 3;
  const int m0 = mb * 128, n0 = (nb & 7) * 128;
  const u16* W = sel == 0 ? wq : (sel == 1 ? wk : wv);
  const float* bias = sel == 0 ? bq : (sel == 1 ? bk : bv);

  const int lane = threadIdx.x & 63, w = threadIdx.x >> 6;
  const int wr = w >> 1, wc = w & 1, g = lane >> 4, c = lane & 15;
  const int bb = m0 >> 11;
  const int lbase = (m0 & 2047) + wr * 64;

  f32x4 acc[4][4];
#pragma unroll
  for (int i = 0; i < 4; ++i)
#pragma unroll
    for (int j = 0; j < 4; ++j) acc[i][j] = f32x4{0.f, 0.f, 0.f, 0.f};

  if (sel < 2) {  // Q or K: swapped -> reg-dim = n = (h,p); packed p-stores
    gemm_tile<true>(xb, W, m0, n0, As, Bs, acc);
    u16* dst = sel == 0 ? qb : kb;
    const float scale = (sel == 0) ? kQScale : 1.0f;
#pragma unroll
    for (int fj = 0; fj < 4; ++fj) {
      const int n4 = n0 + wc * 64 + fj * 16 + g * 4;
      const float4 b4 = *reinterpret_cast<const float4*>(&bias[n4]);
      const int hh = n4 >> 6, p0 = n4 & 63;
      u16* base = dst + ((size_t)(bb * kH + hh)) * kL * kP + p0;
#pragma unroll
      for (int fi = 0; fi < 4; ++fi) {
        const int l = lbase + fi * 16 + c;
        bf16x4 o;
        o[0] = (__bf16)((acc[fj][fi][0] + b4.x) * scale);
        o[1] = (__bf16)((acc[fj][fi][1] + b4.y) * scale);
        o[2] = (__bf16)((acc[fj][fi][2] + b4.z) * scale);
        o[3] = (__bf16)((acc[fj][fi][3] + b4.w) * scale);
        *reinterpret_cast<bf16x4*>(base + (size_t)l * kP) = o;
      }
    }
  } else {  // V: unswapped -> reg-dim = m = l; packed l-stores into V^T
    gemm_tile<false>(xb, W, m0, n0, As, Bs, acc);
#pragma unroll
    for (int fj = 0; fj < 4; ++fj) {
      const int n = n0 + wc * 64 + fj * 16 + c;
      const float bv_ = bias[n];
      const int hh = n >> 6, p = n & 63;
      u16* base = vtb + (((size_t)(bb * kH + hh)) * kP + p) * kL;
#pragma unroll
      for (int fi = 0; fi < 4; ++fi) {
        const int l4 = lbase + fi * 16 + g * 4;
        bf16x4 o;
#pragma unroll
        for (int r = 0; r < 4; ++r) o[r] = (__bf16)(acc[fi][fj][r] + bv_);
        *reinterpret_cast<bf16x4*>(base + l4) = o;
      }
    }
  }
}

// ---------------------------------------------------------------- output GEMM (R10-proven)
// 8 waves (512 thr), 128x128 tile, wave tile 64x32 (wr=w>>2, wc=w&3).
// Grid 256 = 1 block/CU. XCD-chunked: logical = (hw&7)*32 + hw>>3.
__global__ __launch_bounds__(512) void out_kernel(
    const u16* __restrict__ ob, const u16* __restrict__ wo,
    const float* __restrict__ bo, float* __restrict__ out) {
  __shared__ u16 As[128 * 32], Bs[128 * 32];
  const int hw = blockIdx.x;
  const int logical = (hw & 7) * 32 + (hw >> 3);
  const int m0 = (logical & 31) * 128, n0 = (logical >> 5) * 128;

  const int tid = threadIdx.x;
  const int w = tid >> 6, lane = tid & 63;
  const int wr = w >> 2, wc = w & 3;
  const int g = lane >> 4, c = lane & 15;
  const int srow = lane >> 2;
  const int skoff = ((lane & 3) ^ (srow & 3)) * 8;
  const int rsl0 = (g ^ (c & 3)) * 8;

  f32x4 acc[2][4];
#pragma unroll
  for (int i = 0; i < 2; ++i)
#pragma unroll
    for (int j = 0; j < 4; ++j) acc[i][j] = f32x4{0.f, 0.f, 0.f, 0.f};

  for (int k0 = 0; k0 < kD; k0 += 32) {
    __syncthreads();
    {  // each wave stages 16 rows of A and of W
      const u16* ga = ob + (size_t)(m0 + w * 16 + srow) * kD + k0 + skoff;
      gload16(ga, As + (w * 16) * 32);
      const u16* gb = wo + (size_t)(n0 + w * 16 + srow) * kD + k0 + skoff;
      gload16(gb, Bs + (w * 16) * 32);
    }
    __syncthreads();

    bf16x8 af[4], bfr[2];
#pragma unroll
    for (int f = 0; f < 4; ++f)
      af[f] = *reinterpret_cast<const bf16x8*>(As + (wr * 64 + f * 16 + c) * 32 + rsl0);
#pragma unroll
    for (int f = 0; f < 2; ++f)
      bfr[f] = *reinterpret_cast<const bf16x8*>(Bs + (wc * 32 + f * 16 + c) * 32 + rsl0);
#pragma unroll
    for (int fj = 0; fj < 2; ++fj)
#pragma unroll
      for (int fi = 0; fi < 4; ++fi)
        acc[fj][fi] = __builtin_amdgcn_mfma_f32_16x16x32_bf16(bfr[fj], af[fi], acc[fj][fi], 0, 0, 0);
  }

  // epilogue: reg-dim = n -> float4 stores
#pragma unroll
  for (int fj = 0; fj < 2; ++fj) {
    const int n4 = n0 + wc * 32 + fj * 16 + g * 4;
    const float4 b4 = *reinterpret_cast<const float4*>(&bo[n4]);
#pragma unroll
    for (int fi = 0; fi < 4; ++fi) {
      const int m = m0 + wr * 64 + fi * 16 + c;
      float4 o;
      o.x = acc[fj][fi][0] + b4.x;
      o.y = acc[fj][fi][1] + b4.y;
      o.z = acc[fj][fi][2] + b4.z;
      o.w = acc[fj][fi][3] + b4.w;
      *reinterpret_cast<float4*>(&out[(size_t)m * kD + n4]) = o;
    }
  }
}

// ---------------------------------------------------------------- flash attention (R16-proven)
// 1D grid 512 = 8 XCDs x 64, XCD-chunked: logical = (hw&7)*64 + hw>>3.
// Each XCD gets 4 (h,b) pairs x 16 q-blocks -> K/V working set 2 MB/XCD
// (L2-fits), each K/V panel reused 16x from L2 instead of re-fetched.
// 8 waves x 16 queries = 128 queries/block, KVBLK=64 shared by all waves.
// No max pass (exp2-domain bounded), per-lane Srun, unroll x2,
// XOR-swizzled K/V/P LDS, setprio on MFMA clusters.
__global__ __launch_bounds__(512, 2) void attn_kernel(
    const u16* __restrict__ qb, const u16* __restrict__ kb,
    const u16* __restrict__ vtb, u16* __restrict__ ob) {
  // [buf][K=0/V=1][64 rows][128 bytes, swizzled: 16B slot ^= row&7]
  __shared__ __align__(16) char kvs[2][2][8192];
  __shared__ __align__(16) char pts[8][2048];  // per-wave P^T [16][128B swizzled]
  const int tid = threadIdx.x, w = tid >> 6, lane = tid & 63;
  const int g = lane >> 4, c = lane & 15;
  const int hw = blockIdx.x;                      // 512 = 8 XCDs x 64
  const int logical = (hw & 7) * 64 + (hw >> 3);  // bijective
  const int qblk = logical & 15;
  const int hb = logical >> 4;                    // 0..31
  const int h = hb & 15, b = hb >> 4;
  const size_t hoff = ((size_t)(b * kH + h)) * kL * kP;
  const char* Qg = (const char*)(qb + hoff);
  const char* Kg = (const char*)(kb + hoff);
  const char* Vg = (const char*)(vtb + hoff);
  const int q0 = qblk * 128 + w * 16;

  // ---- staging: wave w stages rows w*8..w*8+7 of K and of V^T
  const int lrow = lane >> 3;
  const int spb = ((lane & 7) ^ lrow) << 4;  // pre-swizzled source byte col
  const char* kp = Kg + (size_t)(w * 8 + lrow) * 128 + spb;
  const char* vp = Vg + (size_t)(w * 8 + lrow) * (kL * 2) + spb;

  auto stage = [&](int buf) {
    gload16(kp, &kvs[buf][0][w * 1024]);
    gload16(vp, &kvs[buf][1][w * 1024]);
    kp += 64 * 128;  // next 64 key rows
    vp += 128;       // next 64 keys (2B each)
  };

  // ---- hoisted per-lane LDS byte offsets
  const int csw = (c & 7) << 4;
  const int kvb0 = c * 128 + ((g * 16) ^ csw);
  const int kvb1 = c * 128 + ((64 + g * 16) ^ csw);
  char* myPt = &pts[w][0];

  // Q fragments (16 rows x 64), hoisted
  bf16x8 qf[2];
#pragma unroll
  for (int kc = 0; kc < 2; ++kc)
    qf[kc] = *reinterpret_cast<const bf16x8*>(Qg + (size_t)(q0 + c) * 128 + kc * 64 + g * 16);

  f32x4 oacc[4];
#pragma unroll
  for (int pt = 0; pt < 4; ++pt) oacc[pt] = f32x4{0.f, 0.f, 0.f, 0.f};
  float Srun = 0.f;  // per-lane partial; reduced once at the end

  stage(0);
  __syncthreads();

  constexpr int NT = kL / 64;  // 32
  auto body = [&](int cur, int t) {
    if (t + 1 < NT) stage(cur ^ 1);
    const char* Ks = &kvs[cur][0][0];
    const char* Vs = &kvs[cur][1][0];

    // QK^T: s[lt] = S[key = lt*16+g*4+r][query = c]  (exp2 domain)
    f32x4 s[4];
    __builtin_amdgcn_s_setprio(1);
#pragma unroll
    for (int lt = 0; lt < 4; ++lt) {
      bf16x8 k0 = *reinterpret_cast<const bf16x8*>(Ks + lt * 2048 + kvb0);
      bf16x8 k1 = *reinterpret_cast<const bf16x8*>(Ks + lt * 2048 + kvb1);
      f32x4 z = f32x4{0.f, 0.f, 0.f, 0.f};
      z = __builtin_amdgcn_mfma_f32_16x16x32_bf16(k0, qf[0], z, 0, 0, 0);
      z = __builtin_amdgcn_mfma_f32_16x16x32_bf16(k1, qf[1], z, 0, 0, 0);
      s[lt] = z;
    }
    __builtin_amdgcn_s_setprio(0);

    // P = exp2(s); pack bf16x4, swizzled 8B stores (XOR wraps FULL col offset)
    float tsum = 0.f;
#pragma unroll
    for (int lt = 0; lt < 4; ++lt) {
      bf16x4 pv;
#pragma unroll
      for (int r = 0; r < 4; ++r) {
        float p = __builtin_amdgcn_exp2f(s[lt][r]);
        tsum += p;
        pv[r] = (__bf16)p;
      }
      *reinterpret_cast<bf16x4*>(myPt + c * 128 + ((lt * 32 + g * 8) ^ csw)) = pv;
    }
    Srun += tsum;

    // PV: A = P^T rows (query), B = Vt rows (p)
    bf16x8 pf0 = *reinterpret_cast<const bf16x8*>(myPt + kvb0);
    bf16x8 pf1 = *reinterpret_cast<const bf16x8*>(myPt + kvb1);
    __builtin_amdgcn_s_setprio(1);
#pragma unroll
    for (int pt = 0; pt < 4; ++pt) {
      bf16x8 v0 = *reinterpret_cast<const bf16x8*>(Vs + pt * 2048 + kvb0);
      bf16x8 v1 = *reinterpret_cast<const bf16x8*>(Vs + pt * 2048 + kvb1);
      oacc[pt] = __builtin_amdgcn_mfma_f32_16x16x32_bf16(pf0, v0, oacc[pt], 0, 0, 0);
      oacc[pt] = __builtin_amdgcn_mfma_f32_16x16x32_bf16(pf1, v1, oacc[pt], 0, 0, 0);
    }
    __builtin_amdgcn_s_setprio(0);
    __syncthreads();
  };

  for (int t = 0; t < NT; t += 2) {
    body(0, t);
    body(1, t + 1);
  }

  // reduce Srun across the 4 lane-groups (same query c)
  Srun += __shfl_xor(Srun, 16, 64);
  Srun += __shfl_xor(Srun, 32, 64);

  // normalize, store to o_buf [B, L, D]
  float rs = 1.f / Srun;
  float fr[4];
#pragma unroll
  for (int r = 0; r < 4; ++r) fr[r] = __shfl(rs, g * 4 + r, 64);
#pragma unroll
  for (int pt = 0; pt < 4; ++pt)
#pragma unroll
    for (int r = 0; r < 4; ++r) {
      int q = q0 + g * 4 + r;
      ob[((size_t)(b * kL + q)) * kD + h * kP + pt * 16 + c] = f2bf(oacc[pt][r] * fr[r]);
    }
}

// ---------------------------------------------------------------- launch
extern "C" void kernel_launch(void* const* d_in, const int* in_sizes, int n_in,
                              void* d_out, int out_size, void* d_ws, size_t ws_size,
                              hipStream_t stream) {
  (void)in_sizes; (void)n_in; (void)out_size; (void)ws_size;
  const float* x  = (const float*)d_in[0];
  const float* Wq = (const float*)d_in[1];
  const float* bq = (const float*)d_in[2];
  const float* Wk = (const float*)d_in[3];
  const float* bk = (const float*)d_in[4];
  const float* Wv = (const float*)d_in[5];
  const float* bv = (const float*)d_in[6];
  const float* Wo = (const float*)d_in[7];
  const float* bo = (const float*)d_in[8];
  float* out = (float*)d_out;

  char* ws = (char*)d_ws;
  u16* xb  = (u16*)(ws);                     // 8 MiB; reused as o_buf after QKV
  u16* wqb = (u16*)(ws + (8u << 20));
  u16* wkb = (u16*)(ws + (10u << 20));
  u16* wvb = (u16*)(ws + (12u << 20));
  u16* wob = (u16*)(ws + (14u << 20));
  u16* qb  = (u16*)(ws + (16u << 20));       // [B,H,L,P] (pre-scaled, exp2 domain)
  u16* kb  = (u16*)(ws + (24u << 20));       // [B,H,L,P]
  u16* vtb = (u16*)(ws + (32u << 20));       // [B,H,P,L]

  cvt_all<<<8192, 256, 0, stream>>>(x, Wq, Wk, Wv, Wo, xb, wqb, wkb, wvb, wob);

  qkv_kernel<<<768, 256, 0, stream>>>(
      xb, wqb, wkb, wvb, bq, bk, bv, qb, kb, vtb);

  attn_kernel<<<512, 512, 0, stream>>>(qb, kb, vtb, xb);

  out_kernel<<<256, 512, 0, stream>>>(xb, wob, bo, out);
}